// Round 1
// baseline (513.240 us; speedup 1.0000x reference)
//
#include <hip/hip_runtime.h>

// FAVOR+ attention, B=8 H=4 L=4096 D=128 M=640, fp32 in/out.
// Math: out = (phi_q @ ctx) / (phi_q @ ksum), phi scales exp(eps)/sqrt(M) and
// per-row e^{-g_q} cancel in the ratio -> dropped. Only g_k kept.
// All 4 big GEMMs via v_mfma_f32_16x16x32_bf16 (NT form, fp32 accum).

#define BH 32
#define LSEQ 4096
#define DIM 128
#define MFEAT 640
#define LDSW 136   // padded row stride (elements) for 128-wide LDS tiles; 136*2=272 B, 16B-aligned rows

typedef __bf16 bf16x8 __attribute__((ext_vector_type(8)));
typedef float f32x4 __attribute__((ext_vector_type(4)));

__device__ __forceinline__ unsigned short f2b(float f) {
    union { float f; unsigned u; } c; c.f = f;
    unsigned u = c.u + 0x7FFFu + ((c.u >> 16) & 1u);   // RNE bf16 (finite inputs only)
    return (unsigned short)(u >> 16);
}
__device__ __forceinline__ float b2f(unsigned short h) {
    union { unsigned u; float f; } c; c.u = ((unsigned)h) << 16;
    return c.f;
}
__device__ __forceinline__ bf16x8 ld8(const unsigned short* p) {
    union { uint4 q; bf16x8 v; } c;
    c.q = *reinterpret_cast<const uint4*>(p);
    return c.v;
}

// ---------------- prep: rows of 128, optional scale + g = 0.5*sum((x*s)^2) ----------------
__global__ void prep_rows(const float* __restrict__ src, unsigned short* __restrict__ dst,
                          float* __restrict__ gout, int nrows, float scale)
{
    const int row = blockIdx.x * 8 + (threadIdx.x >> 5);
    const int ln = threadIdx.x & 31;
    if (row >= nrows) return;
    const float4 f = *reinterpret_cast<const float4*>(src + (size_t)row * DIM + ln * 4);
    const float a = f.x * scale, b = f.y * scale, c = f.z * scale, d = f.w * scale;
    ushort4 o; o.x = f2b(a); o.y = f2b(b); o.z = f2b(c); o.w = f2b(d);
    *reinterpret_cast<ushort4*>(dst + (size_t)row * DIM + ln * 4) = o;
    if (gout != nullptr) {
        float ss = a * a + b * b + c * c + d * d;
        #pragma unroll
        for (int off = 16; off >= 1; off >>= 1) ss += __shfl_xor(ss, off, 64); // stays within 32-lane row group
        if (ln == 0) gout[row] = 0.5f * ss;   // = sum(x^2)/(2*sqrt(d)) since s^2 = 1/sqrt(d)
    }
}

// ---------------- prep: v [bh][l][e] fp32 -> vt [bh][e][l] bf16 ----------------
__global__ void prep_vt_k(const float* __restrict__ v, unsigned short* __restrict__ vt)
{
    __shared__ float tile[64][129];
    const int bh = blockIdx.x >> 6;
    const int l0 = (blockIdx.x & 63) * 64;
    const int tid = threadIdx.x;
    const float* vb = v + ((size_t)bh * LSEQ + l0) * DIM;
    for (int u = tid; u < 2048; u += 256) {
        const int r = u >> 5, c = (u & 31) * 4;
        const float4 f = *reinterpret_cast<const float4*>(vb + (size_t)r * DIM + c);
        tile[r][c] = f.x; tile[r][c + 1] = f.y; tile[r][c + 2] = f.z; tile[r][c + 3] = f.w;
    }
    __syncthreads();
    const int e = tid >> 1, hf = tid & 1;
    unsigned w[16];
    #pragma unroll
    for (int j = 0; j < 16; ++j) {
        w[j] = ((unsigned)f2b(tile[hf * 32 + 2 * j][e])) |
               (((unsigned)f2b(tile[hf * 32 + 2 * j + 1][e])) << 16);
    }
    unsigned short* dst = vt + ((size_t)bh * DIM + e) * LSEQ + l0 + hf * 32;
    uint4* d4 = reinterpret_cast<uint4*>(dst);
    d4[0] = make_uint4(w[0], w[1], w[2], w[3]);
    d4[1] = make_uint4(w[4], w[5], w[6], w[7]);
    d4[2] = make_uint4(w[8], w[9], w[10], w[11]);
    d4[3] = make_uint4(w[12], w[13], w[14], w[15]);
}

// ---------------- kernel 1: ctx[m][e] += phi_k^T @ v ; ksum[m] += sum_l phi_k ----------------
__global__ __launch_bounds__(256, 2) void k1_ctx(
    const unsigned short* __restrict__ kb, const float* __restrict__ gk,
    const unsigned short* __restrict__ projb, const unsigned short* __restrict__ vt,
    float* __restrict__ ctx, float* __restrict__ ksum)
{
    __shared__ __align__(16) unsigned short sProj[128 * LDSW];
    __shared__ __align__(16) unsigned short sPhi[128 * LDSW];  // [m][l]
    __shared__ float sG[128];
    __shared__ float sKred[256];

    const int tid = threadIdx.x;
    const int wave = tid >> 6, lane = tid & 63;
    const int quad = lane >> 4, lx = lane & 15;

    // XCD swizzle: same-bh blocks land on same XCD (blockIdx%8 heuristic)
    const int xcd = blockIdx.x & 7;
    const int kk = blockIdx.x >> 3;           // 0..79
    const int bh = xcd * 4 + kk / 20;
    const int t20 = kk % 20;
    const int part = t20 / 5;                 // L split 0..3
    const int mc = t20 % 5;                   // m-chunk 0..4 (128 each)
    const int m0 = mc * 128;
    const int lbase = part * 1024;

    for (int u = tid; u < 128 * 16; u += 256) {
        const int r = u >> 4, c = (u & 15) * 8;
        *reinterpret_cast<uint4*>(&sProj[r * LDSW + c]) =
            *reinterpret_cast<const uint4*>(projb + (size_t)(m0 + r) * DIM + c);
    }

    f32x4 acc[8][2];
    #pragma unroll
    for (int i = 0; i < 8; ++i)
        #pragma unroll
        for (int j = 0; j < 2; ++j) acc[i][j] = f32x4{0.f, 0.f, 0.f, 0.f};
    float ksacc = 0.f;

    const unsigned short* kbase = kb + (size_t)bh * (LSEQ * DIM);
    const unsigned short* vbase = vt + (size_t)bh * (DIM * LSEQ);
    const float* gbase = gk + (size_t)bh * LSEQ;

    __syncthreads();

    for (int tile = 0; tile < 8; ++tile) {
        const int l0 = lbase + tile * 128;
        if (tid < 128) sG[tid] = gbase[l0 + tid];

        // MFMA1: S[l(128), m(128)] = k_tile . projchunk^T ; wave owns 32 l-rows
        bf16x8 afr[2][4];
        #pragma unroll
        for (int lt = 0; lt < 2; ++lt)
            #pragma unroll
            for (int ks = 0; ks < 4; ++ks)
                afr[lt][ks] = ld8(kbase + (size_t)(l0 + wave * 32 + lt * 16 + lx) * DIM + ks * 32 + quad * 8);

        f32x4 S[2][8];
        #pragma unroll
        for (int lt = 0; lt < 2; ++lt)
            #pragma unroll
            for (int mt = 0; mt < 8; ++mt) S[lt][mt] = f32x4{0.f, 0.f, 0.f, 0.f};
        #pragma unroll
        for (int ks = 0; ks < 4; ++ks) {
            #pragma unroll
            for (int mt = 0; mt < 8; ++mt) {
                const bf16x8 bfr = ld8(&sProj[(mt * 16 + lx) * LDSW + ks * 32 + quad * 8]);
                S[0][mt] = __builtin_amdgcn_mfma_f32_16x16x32_bf16(afr[0][ks], bfr, S[0][mt], 0, 0, 0);
                S[1][mt] = __builtin_amdgcn_mfma_f32_16x16x32_bf16(afr[1][ks], bfr, S[1][mt], 0, 0, 0);
            }
        }
        __syncthreads();   // all readers of previous tile's sPhi done; sG visible
        #pragma unroll
        for (int lt = 0; lt < 2; ++lt) {
            #pragma unroll
            for (int r = 0; r < 4; ++r) {
                const int lrow = wave * 32 + lt * 16 + quad * 4 + r;
                const float g = sG[lrow];
                #pragma unroll
                for (int mt = 0; mt < 8; ++mt)
                    sPhi[(mt * 16 + lx) * LDSW + lrow] = f2b(__expf(S[lt][mt][r] - g));
            }
        }
        __syncthreads();
        // ksum partial from same bf16 phi the MFMA consumes
        {
            const int ml = tid >> 1, hf = tid & 1;
            const uint4* prow = reinterpret_cast<const uint4*>(&sPhi[ml * LDSW + hf * 64]);
            float s = 0.f;
            #pragma unroll
            for (int j = 0; j < 8; ++j) {
                const uint4 ph = prow[j];
                s += b2f((unsigned short)(ph.x & 0xffff)) + b2f((unsigned short)(ph.x >> 16))
                   + b2f((unsigned short)(ph.y & 0xffff)) + b2f((unsigned short)(ph.y >> 16))
                   + b2f((unsigned short)(ph.z & 0xffff)) + b2f((unsigned short)(ph.z >> 16))
                   + b2f((unsigned short)(ph.w & 0xffff)) + b2f((unsigned short)(ph.w >> 16));
            }
            ksacc += s;
        }
        // MFMA2: ctx[m(128), e(32/wave)] += phi^T . v ; B-frags from vt rows (global, L2-hot)
        #pragma unroll
        for (int ks = 0; ks < 4; ++ks) {
            const bf16x8 bfr0 = ld8(vbase + (size_t)(wave * 32 + lx) * LSEQ + l0 + ks * 32 + quad * 8);
            const bf16x8 bfr1 = ld8(vbase + (size_t)(wave * 32 + 16 + lx) * LSEQ + l0 + ks * 32 + quad * 8);
            #pragma unroll
            for (int mt = 0; mt < 8; ++mt) {
                const bf16x8 afr2 = ld8(&sPhi[(mt * 16 + lx) * LDSW + ks * 32 + quad * 8]);
                acc[mt][0] = __builtin_amdgcn_mfma_f32_16x16x32_bf16(afr2, bfr0, acc[mt][0], 0, 0, 0);
                acc[mt][1] = __builtin_amdgcn_mfma_f32_16x16x32_bf16(afr2, bfr1, acc[mt][1], 0, 0, 0);
            }
        }
    }

    #pragma unroll
    for (int mt = 0; mt < 8; ++mt)
        #pragma unroll
        for (int r = 0; r < 4; ++r) {
            const size_t rowoff = ((size_t)bh * MFEAT + m0 + mt * 16 + quad * 4 + r) * DIM;
            atomicAdd(&ctx[rowoff + wave * 32 + lx], acc[mt][0][r]);
            atomicAdd(&ctx[rowoff + wave * 32 + 16 + lx], acc[mt][1][r]);
        }
    sKred[tid] = ksacc;
    __syncthreads();
    if (tid < 128)
        atomicAdd(&ksum[(size_t)bh * MFEAT + m0 + tid], sKred[2 * tid] + sKred[2 * tid + 1]);
}

// ---------------- ctx fp32 [bh][m][e] -> ctxb bf16 [bh][e][m] ----------------
__global__ void k_cvt_ctx(const float* __restrict__ ctx, unsigned short* __restrict__ ctxb)
{
    __shared__ float tile[64][132];
    const int bh = blockIdx.x / 10;
    const int m0 = (blockIdx.x % 10) * 64;
    const int tid = threadIdx.x;
    const float* cb = ctx + ((size_t)bh * MFEAT + m0) * DIM;
    for (int u = tid; u < 2048; u += 256) {
        const int r = u >> 5, c = (u & 31) * 4;
        const float4 f = *reinterpret_cast<const float4*>(cb + (size_t)r * DIM + c);
        tile[r][c] = f.x; tile[r][c + 1] = f.y; tile[r][c + 2] = f.z; tile[r][c + 3] = f.w;
    }
    __syncthreads();
    const int e = tid >> 1, hf = tid & 1;
    unsigned w[16];
    #pragma unroll
    for (int j = 0; j < 16; ++j) {
        w[j] = ((unsigned)f2b(tile[hf * 32 + 2 * j][e])) |
               (((unsigned)f2b(tile[hf * 32 + 2 * j + 1][e])) << 16);
    }
    unsigned short* dst = ctxb + ((size_t)bh * DIM + e) * MFEAT + m0 + hf * 32;
    uint4* d4 = reinterpret_cast<uint4*>(dst);
    d4[0] = make_uint4(w[0], w[1], w[2], w[3]);
    d4[1] = make_uint4(w[4], w[5], w[6], w[7]);
    d4[2] = make_uint4(w[8], w[9], w[10], w[11]);
    d4[3] = make_uint4(w[12], w[13], w[14], w[15]);
}

// ---------------- kernel 2: out = (phi_q @ ctx) / (phi_q @ ksum) ----------------
__global__ __launch_bounds__(256, 2) void k2_out(
    const float* __restrict__ q, const unsigned short* __restrict__ projb,
    const unsigned short* __restrict__ ctxb, const float* __restrict__ ksum,
    float* __restrict__ out, float scale)
{
    __shared__ __align__(16) unsigned short sPhi[128 * LDSW];  // [l][m]
    __shared__ float sKs[MFEAT];
    __shared__ float sDred[256];

    const int tid = threadIdx.x;
    const int wave = tid >> 6, lane = tid & 63;
    const int quad = lane >> 4, lx = lane & 15;

    const int bh = blockIdx.x >> 5;
    const int l0 = (blockIdx.x & 31) * 128;

    for (int i = tid; i < MFEAT; i += 256) sKs[i] = ksum[(size_t)bh * MFEAT + i];

    // q A-frags: fp32 -> scaled bf16 in-reg, held for all chunks (32 VGPRs/lane)
    bf16x8 qa[2][4];
    #pragma unroll
    for (int lt = 0; lt < 2; ++lt)
        #pragma unroll
        for (int ks = 0; ks < 4; ++ks) {
            const float* p = q + ((size_t)bh * LSEQ + l0 + wave * 32 + lt * 16 + lx) * DIM + ks * 32 + quad * 8;
            const float4 f0 = *reinterpret_cast<const float4*>(p);
            const float4 f1 = *reinterpret_cast<const float4*>(p + 4);
            union { unsigned u[4]; bf16x8 v; } c;
            c.u[0] = ((unsigned)f2b(f0.x * scale)) | (((unsigned)f2b(f0.y * scale)) << 16);
            c.u[1] = ((unsigned)f2b(f0.z * scale)) | (((unsigned)f2b(f0.w * scale)) << 16);
            c.u[2] = ((unsigned)f2b(f1.x * scale)) | (((unsigned)f2b(f1.y * scale)) << 16);
            c.u[3] = ((unsigned)f2b(f1.z * scale)) | (((unsigned)f2b(f1.w * scale)) << 16);
            qa[lt][ks] = c.v;
        }

    f32x4 oacc[2][8];
    #pragma unroll
    for (int i = 0; i < 2; ++i)
        #pragma unroll
        for (int j = 0; j < 8; ++j) oacc[i][j] = f32x4{0.f, 0.f, 0.f, 0.f};
    float dacc = 0.f;
    __syncthreads();

    for (int c5 = 0; c5 < 5; ++c5) {
        const int m0 = c5 * 128;
        // MFMA1: S[l(32/wave), m(128)] = q . projchunk^T ; B-frags straight from global (L2-hot 160KB)
        f32x4 S[2][8];
        #pragma unroll
        for (int lt = 0; lt < 2; ++lt)
            #pragma unroll
            for (int mt = 0; mt < 8; ++mt) S[lt][mt] = f32x4{0.f, 0.f, 0.f, 0.f};
        #pragma unroll
        for (int ks = 0; ks < 4; ++ks) {
            #pragma unroll
            for (int mt = 0; mt < 8; ++mt) {
                const bf16x8 pb = ld8(projb + (size_t)(m0 + mt * 16 + lx) * DIM + ks * 32 + quad * 8);
                S[0][mt] = __builtin_amdgcn_mfma_f32_16x16x32_bf16(qa[0][ks], pb, S[0][mt], 0, 0, 0);
                S[1][mt] = __builtin_amdgcn_mfma_f32_16x16x32_bf16(qa[1][ks], pb, S[1][mt], 0, 0, 0);
            }
        }
        __syncthreads();   // previous chunk's sPhi readers done
        #pragma unroll
        for (int lt = 0; lt < 2; ++lt) {
            #pragma unroll
            for (int r = 0; r < 4; ++r) {
                const int lrow = wave * 32 + lt * 16 + quad * 4 + r;
                #pragma unroll
                for (int mt = 0; mt < 8; ++mt)
                    sPhi[lrow * LDSW + mt * 16 + lx] = f2b(__expf(S[lt][mt][r]));  // g_q cancels in ratio
            }
        }
        __syncthreads();
        // D partial: uses same bf16 phi as MFMA numerator (consistency for the division)
        {
            const int l = tid >> 1, hf = tid & 1;
            const uint4* prow = reinterpret_cast<const uint4*>(&sPhi[l * LDSW + hf * 64]);
            const float4* kp = reinterpret_cast<const float4*>(&sKs[m0 + hf * 64]);
            float s = 0.f;
            #pragma unroll
            for (int j = 0; j < 8; ++j) {
                const uint4 ph = prow[j];
                const float4 ka = kp[2 * j];
                const float4 kb2 = kp[2 * j + 1];
                s += b2f((unsigned short)(ph.x & 0xffff)) * ka.x + b2f((unsigned short)(ph.x >> 16)) * ka.y
                   + b2f((unsigned short)(ph.y & 0xffff)) * ka.z + b2f((unsigned short)(ph.y >> 16)) * ka.w
                   + b2f((unsigned short)(ph.z & 0xffff)) * kb2.x + b2f((unsigned short)(ph.z >> 16)) * kb2.y
                   + b2f((unsigned short)(ph.w & 0xffff)) * kb2.z + b2f((unsigned short)(ph.w >> 16)) * kb2.w;
            }
            dacc += s;
        }
        // MFMA2: out[l(32/wave), e(128)] += phi_q . ctx ; B-frags = ctxb rows (global, L2-hot)
        #pragma unroll
        for (int ks = 0; ks < 4; ++ks) {
            const bf16x8 pa0 = ld8(&sPhi[(wave * 32 + lx) * LDSW + m0 * 0 + ks * 32 + quad * 8]);
            const bf16x8 pa1 = ld8(&sPhi[(wave * 32 + 16 + lx) * LDSW + ks * 32 + quad * 8]);
            #pragma unroll
            for (int et = 0; et < 8; ++et) {
                const bf16x8 cb = ld8(ctxb + ((size_t)bh * DIM + et * 16 + lx) * MFEAT + m0 + ks * 32 + quad * 8);
                oacc[0][et] = __builtin_amdgcn_mfma_f32_16x16x32_bf16(pa0, cb, oacc[0][et], 0, 0, 0);
                oacc[1][et] = __builtin_amdgcn_mfma_f32_16x16x32_bf16(pa1, cb, oacc[1][et], 0, 0, 0);
            }
        }
    }

    sDred[tid] = dacc;
    __syncthreads();
    #pragma unroll
    for (int lt = 0; lt < 2; ++lt)
        #pragma unroll
        for (int r = 0; r < 4; ++r) {
            const int lrow = wave * 32 + lt * 16 + quad * 4 + r;
            const float Dv = sDred[2 * lrow] + sDred[2 * lrow + 1];
            const float inv = 1.0f / Dv;
            float* ob = out + ((size_t)bh * LSEQ + l0 + lrow) * DIM;
            #pragma unroll
            for (int et = 0; et < 8; ++et)
                ob[et * 16 + lx] = oacc[lt][et][r] * inv;
        }
}

extern "C" void kernel_launch(void* const* d_in, const int* in_sizes, int n_in,
                              void* d_out, int out_size, void* d_ws, size_t ws_size,
                              hipStream_t stream)
{
    (void)in_sizes; (void)n_in; (void)out_size; (void)ws_size;
    const float* q = (const float*)d_in[0];
    const float* k = (const float*)d_in[1];
    const float* v = (const float*)d_in[2];
    const float* proj = (const float*)d_in[3];
    float* out = (float*)d_out;
    char* ws = (char*)d_ws;

    // ws layout (bytes), total 88,850,432
    unsigned short* kb    = (unsigned short*)(ws);                  // 33,554,432
    unsigned short* vt    = (unsigned short*)(ws + 33554432);       // 33,554,432
    unsigned short* projb = (unsigned short*)(ws + 67108864);       //    163,840
    float*          gk    = (float*)         (ws + 67272704);       //    524,288
    float*          ctx   = (float*)         (ws + 67796992);       // 10,485,760
    float*          ksum  = (float*)         (ws + 78282752);       //     81,920
    unsigned short* ctxb  = (unsigned short*)(ws + 78364672);       // 10,485,760

    const float s = 0.2973017787506803f;  // 1/128^0.25

    hipMemsetAsync(ctx, 0, 10485760 + 81920, stream);               // ctx + ksum (atomic targets)
    prep_rows<<<16384, 256, 0, stream>>>(k, kb, gk, BH * LSEQ, s);
    prep_rows<<<80, 256, 0, stream>>>(proj, projb, nullptr, MFEAT, 1.0f);
    prep_vt_k<<<BH * 64, 256, 0, stream>>>(v, vt);
    k1_ctx<<<640, 256, 0, stream>>>(kb, gk, projb, vt, ctx, ksum);
    k_cvt_ctx<<<320, 256, 0, stream>>>(ctx, ctxb);
    k2_out<<<1024, 256, 0, stream>>>(q, projb, ctxb, ksum, out, s);
}